// Round 2
// baseline (199.442 us; speedup 1.0000x reference)
//
#include <hip/hip_runtime.h>
#include <cstdint>

#define PPB 8      // points per block
#define ROW 351    // 32 + 32*4*2 + 3 + 3*10*2
#define CH 32

__global__ __launch_bounds__(256)
void embed_voxel_kernel(const float* __restrict__ xyz,
                        const float* __restrict__ table,
                        const int*   __restrict__ vmap,
                        const float* __restrict__ voff,
                        const float* __restrict__ vsize,
                        const int*   __restrict__ vshape,
                        float* __restrict__ out,
                        int npts)
{
    __shared__ __align__(16) float rows[PPB * ROW];   // 11232 B
    __shared__ __align__(16) float inst[PPB * 8];     // 256 B

    const int tid = threadIdx.x;
    const int p   = tid >> 5;            // point within block
    const int ch  = tid & 31;            // channel
    const int n   = blockIdx.x * PPB + p;   // npts % PPB == 0

    const float vs = vsize[0];
    const int sx = vshape[0], sy = vshape[1], sz = vshape[2];

    float xyzr[3], fr[3];
    int q0[3];
    #pragma unroll
    for (int d = 0; d < 3; ++d) {
        float raw = xyz[(size_t)n * 3 + d];
        xyzr[d] = raw;
        float v = (raw + voff[d]) / vs;   // IEEE divide — matches reference floor decisions
        float fl = floorf(v);
        q0[d] = (int)fl;
        fr[d] = v - fl;
    }

    // 8-corner trilinear gather-accumulate (this thread's channel)
    float acc = 0.0f;
    #pragma unroll
    for (int k = 0; k < 8; ++k) {
        const int bx = (k >> 2) & 1, by = (k >> 1) & 1, bz = k & 1;
        const int qx = q0[0] + bx, qy = q0[1] + by, qz = q0[2] + bz;
        const float w = (bx ? fr[0] : 1.0f - fr[0]) *
                        (by ? fr[1] : 1.0f - fr[1]) *
                        (bz ? fr[2] : 1.0f - fr[2]);
        if (qx >= 0 && qy >= 0 && qz >= 0 && qx < sx && qy < sy && qz < sz) {
            const int idx = vmap[((size_t)qx * sy + qy) * sz + qz];
            if (idx >= 0)
                acc += w * table[(size_t)idx * CH + ch];
        }
    }

    // ---- stage outputs into LDS (f32) ----
    float* r = rows + p * ROW;

    // voxel_ftr raw channels [0..31]
    r[ch] = acc;
    // inst features = channels 24..31
    if (ch >= 24) inst[p * 8 + (ch - 24)] = acc;

    // posenc(voxel_ftr, 4): index = 32 + f*64 + s*32 + ch
    #pragma unroll
    for (int f = 0; f < 4; ++f) {
        float s, c;
        __sincosf(acc * (float)(1 << f), &s, &c);
        r[32 + f * 64 + ch]      = s;
        r[32 + f * 64 + 32 + ch] = c;
    }

    // posenc(xyz, 10): raw xyz at 288+d, sin at 291+f*6+d, cos at 291+f*6+3+d
    if (ch < 3) r[288 + ch] = xyzr[ch];
    if (ch < 30) {
        const int f = ch / 3, d = ch % 3;
        float s, c;
        __sincosf(xyzr[d] * (float)(1 << f), &s, &c);
        r[291 + f * 6 + d]     = s;
        r[291 + f * 6 + 3 + d] = c;
    }

    __syncthreads();

    // ---- coalesced write-out ----
    // out0: this block's 8 rows = 2808 contiguous floats = 702 float4 (11232 B, 16B-aligned)
    {
        float4* dst = (float4*)(out + (size_t)blockIdx.x * (PPB * ROW));
        const float4* src = (const float4*)rows;
        for (int i = tid; i < (PPB * ROW) / 4; i += 256)
            dst[i] = src[i];
    }
    // out1: 64 contiguous floats = 16 float4
    if (tid < 16) {
        float4* dst = (float4*)(out + (size_t)npts * ROW + (size_t)blockIdx.x * (PPB * 8));
        dst[tid] = ((const float4*)inst)[tid];
    }
}

extern "C" void kernel_launch(void* const* d_in, const int* in_sizes, int n_in,
                              void* d_out, int out_size, void* d_ws, size_t ws_size,
                              hipStream_t stream) {
    const float* xyz    = (const float*)d_in[0];
    const float* table  = (const float*)d_in[1];
    const int*   vmap   = (const int*)d_in[2];
    const float* voff   = (const float*)d_in[3];
    const float* vsize  = (const float*)d_in[4];
    const int*   vshape = (const int*)d_in[5];
    float* out = (float*)d_out;

    const int npts = in_sizes[0] / 3;      // 262144
    const int blocks = npts / PPB;         // 32768
    embed_voxel_kernel<<<blocks, 256, 0, stream>>>(xyz, table, vmap, voff, vsize,
                                                   vshape, out, npts);
}

// Round 3
// 132.461 us; speedup vs baseline: 1.5057x; 1.5057x over previous
//
#include <hip/hip_runtime.h>
#include <cstdint>

#define PPB 8      // points per block
#define ROW 351    // 32 + 32*4*2 + 3 + 3*10*2
#define CH 32

__global__ __launch_bounds__(256)
void embed_voxel_kernel(const float* __restrict__ xyz,
                        const float* __restrict__ table,
                        const int*   __restrict__ vmap,
                        const float* __restrict__ voff,
                        const float* __restrict__ vsize,
                        const int*   __restrict__ vshape,
                        float* __restrict__ out,
                        int npts)
{
    __shared__ __align__(16) float rows[PPB * ROW];   // 11232 B
    __shared__ __align__(16) float inst[PPB * 8];     // 256 B

    const int tid = threadIdx.x;
    const int p   = tid >> 5;            // point within block
    const int ch  = tid & 31;            // channel
    const int n   = blockIdx.x * PPB + p;   // npts % PPB == 0

    const float vs = vsize[0];
    const int sx = vshape[0], sy = vshape[1], sz = vshape[2];

    float xyzr[3], fr[3];
    int q0[3];
    #pragma unroll
    for (int d = 0; d < 3; ++d) {
        float raw = xyz[(size_t)n * 3 + d];
        xyzr[d] = raw;
        float v = (raw + voff[d]) / vs;   // IEEE divide — matches reference floor decisions
        float fl = floorf(v);
        q0[d] = (int)fl;
        fr[d] = v - fl;
    }

    // ---- Phase 1: 8 independent vmap loads (branchless; clamp OOB to [0,0,0],
    //      zero the weight instead — identical to reference's masked-zero) ----
    int   vidx[8];
    float wts[8];
    #pragma unroll
    for (int k = 0; k < 8; ++k) {
        const int bx = (k >> 2) & 1, by = (k >> 1) & 1, bz = k & 1;
        const int qx = q0[0] + bx, qy = q0[1] + by, qz = q0[2] + bz;
        const bool valid = (qx >= 0) & (qy >= 0) & (qz >= 0) &
                           (qx < sx) & (qy < sy) & (qz < sz);
        const int cqx = valid ? qx : 0;
        const int cqy = valid ? qy : 0;
        const int cqz = valid ? qz : 0;
        vidx[k] = vmap[((size_t)cqx * sy + cqy) * sz + cqz];
        const float w = (bx ? fr[0] : 1.0f - fr[0]) *
                        (by ? fr[1] : 1.0f - fr[1]) *
                        (bz ? fr[2] : 1.0f - fr[2]);
        wts[k] = valid ? w : 0.0f;
    }

    // ---- Phase 2: 8 independent table gathers (clamp negative idx to 0, zero weight) ----
    float ftr[8];
    #pragma unroll
    for (int k = 0; k < 8; ++k) {
        const int id  = vidx[k];
        const int cid = (id >= 0) ? id : 0;
        wts[k] = (id >= 0) ? wts[k] : 0.0f;
        ftr[k] = table[(size_t)cid * CH + ch];
    }

    // ---- Phase 3: weighted sum ----
    float acc = 0.0f;
    #pragma unroll
    for (int k = 0; k < 8; ++k) acc = fmaf(wts[k], ftr[k], acc);

    // ---- stage outputs into LDS (f32) ----
    float* r = rows + p * ROW;

    // voxel_ftr raw channels [0..31]
    r[ch] = acc;
    // inst features = channels 24..31
    if (ch >= 24) inst[p * 8 + (ch - 24)] = acc;

    // posenc(voxel_ftr, 4): index = 32 + f*64 + s*32 + ch
    #pragma unroll
    for (int f = 0; f < 4; ++f) {
        float s, c;
        __sincosf(acc * (float)(1 << f), &s, &c);
        r[32 + f * 64 + ch]      = s;
        r[32 + f * 64 + 32 + ch] = c;
    }

    // posenc(xyz, 10): raw xyz at 288+d, sin at 291+f*6+d, cos at 291+f*6+3+d
    if (ch < 3) r[288 + ch] = xyzr[ch];
    if (ch < 30) {
        const int f = ch / 3, d = ch % 3;
        float s, c;
        __sincosf(xyzr[d] * (float)(1 << f), &s, &c);
        r[291 + f * 6 + d]     = s;
        r[291 + f * 6 + 3 + d] = c;
    }

    __syncthreads();

    // ---- coalesced write-out ----
    // out0: this block's 8 rows = 2808 contiguous floats = 702 float4 (11232 B, 16B-aligned)
    {
        float4* dst = (float4*)(out + (size_t)blockIdx.x * (PPB * ROW));
        const float4* src = (const float4*)rows;
        for (int i = tid; i < (PPB * ROW) / 4; i += 256)
            dst[i] = src[i];
    }
    // out1: 64 contiguous floats = 16 float4
    if (tid < 16) {
        float4* dst = (float4*)(out + (size_t)npts * ROW + (size_t)blockIdx.x * (PPB * 8));
        dst[tid] = ((const float4*)inst)[tid];
    }
}

extern "C" void kernel_launch(void* const* d_in, const int* in_sizes, int n_in,
                              void* d_out, int out_size, void* d_ws, size_t ws_size,
                              hipStream_t stream) {
    const float* xyz    = (const float*)d_in[0];
    const float* table  = (const float*)d_in[1];
    const int*   vmap   = (const int*)d_in[2];
    const float* voff   = (const float*)d_in[3];
    const float* vsize  = (const float*)d_in[4];
    const int*   vshape = (const int*)d_in[5];
    float* out = (float*)d_out;

    const int npts = in_sizes[0] / 3;      // 262144
    const int blocks = npts / PPB;         // 32768
    embed_voxel_kernel<<<blocks, 256, 0, stream>>>(xyz, table, vmap, voff, vsize,
                                                   vshape, out, npts);
}

// Round 5
// 99.747 us; speedup vs baseline: 1.9995x; 1.3280x over previous
//
#include <hip/hip_runtime.h>
#include <cstdint>

#define PPB 8      // points per block
#define ROW 351    // 32 + 32*4*2 + 3 + 3*10*2
#define CH 32

typedef float f32x4 __attribute__((ext_vector_type(4)));

__global__ __launch_bounds__(256)
void embed_voxel_kernel(const float* __restrict__ xyz,
                        const float* __restrict__ table,
                        const int*   __restrict__ vmap,
                        const float* __restrict__ voff,
                        const float* __restrict__ vsize,
                        const int*   __restrict__ vshape,
                        float* __restrict__ out,
                        int npts)
{
    __shared__ __align__(16) float rows[PPB * ROW];   // 11232 B
    __shared__ __align__(16) float inst[PPB * 8];     // 256 B
    __shared__ float sxyz[PPB * 3];                   // raw coords
    __shared__ float sfr[PPB * 3];                    // frac part
    __shared__ int   sq0[PPB * 3];                    // floor coord
    __shared__ float swt[PPB * 8];                    // corner weights
    __shared__ int   sidx[PPB * 8];                   // corner table indices

    const int tid = threadIdx.x;

    // ---- Phase A0: coord math, once per (point,dim) — 24 threads ----
    if (tid < PPB * 3) {
        const float raw = xyz[(size_t)blockIdx.x * (PPB * 3) + tid];
        sxyz[tid] = raw;
        const int d = tid % 3;
        const float v = (raw + voff[d]) / vsize[0];   // IEEE divide, matches reference
        const float fl = floorf(v);
        sq0[tid] = (int)fl;
        sfr[tid] = v - fl;
    }
    __syncthreads();

    // ---- Phase A1: one thread per (point,corner) — 64 threads ----
    if (tid < PPB * 8) {
        const int p = tid >> 3, k = tid & 7;
        const int sx = vshape[0], sy = vshape[1], sz = vshape[2];
        float w = 1.0f;
        bool valid = true;
        int qq[3];
        #pragma unroll
        for (int d = 0; d < 3; ++d) {
            const int b = (k >> (2 - d)) & 1;
            const float fr = sfr[p * 3 + d];
            const int qd = sq0[p * 3 + d] + b;
            w *= b ? fr : 1.0f - fr;
            const int sd = (d == 0) ? sx : (d == 1) ? sy : sz;
            valid = valid && (qd >= 0) && (qd < sd);
            qq[d] = qd;
        }
        const int cqx = valid ? qq[0] : 0;
        const int cqy = valid ? qq[1] : 0;
        const int cqz = valid ? qq[2] : 0;
        const int id = vmap[((size_t)cqx * sy + cqy) * sz + cqz];
        swt[tid]  = (valid && id >= 0) ? w : 0.0f;
        sidx[tid] = (id >= 0) ? id : 0;
    }
    __syncthreads();

    // ---- Phase B: gather + weighted sum, one thread per (point,channel) ----
    const int p  = tid >> 5;
    const int ch = tid & 31;

    float acc = 0.0f;
    #pragma unroll
    for (int k = 0; k < 8; ++k) {
        const int   id = sidx[p * 8 + k];   // LDS broadcast
        const float w  = swt[p * 8 + k];
        acc = fmaf(w, table[(size_t)id * CH + ch], acc);
    }

    // ---- stage outputs into LDS (f32) ----
    float* r = rows + p * ROW;

    r[ch] = acc;                                   // voxel_ftr channels [0..31]
    if (ch >= 24) inst[p * 8 + (ch - 24)] = acc;   // inst = channels 24..31

    // posenc(voxel_ftr, 4): index = 32 + f*64 + s*32 + ch
    #pragma unroll
    for (int f = 0; f < 4; ++f) {
        float s, c;
        __sincosf(acc * (float)(1 << f), &s, &c);
        r[32 + f * 64 + ch]      = s;
        r[32 + f * 64 + 32 + ch] = c;
    }

    // posenc(xyz, 10): raw xyz at 288+d, sin at 291+f*6+d, cos at 291+f*6+3+d
    if (ch < 3) r[288 + ch] = sxyz[p * 3 + ch];
    if (ch < 30) {
        const int f = ch / 3, d = ch % 3;
        float s, c;
        __sincosf(sxyz[p * 3 + d] * (float)(1 << f), &s, &c);
        r[291 + f * 6 + d]     = s;
        r[291 + f * 6 + 3 + d] = c;
    }

    __syncthreads();

    // ---- coalesced non-temporal write-out ----
    // out0: this block's 8 rows = 2808 contiguous floats = 702 float4
    {
        f32x4* dst = (f32x4*)(out + (size_t)blockIdx.x * (PPB * ROW));
        const f32x4* src = (const f32x4*)rows;
        for (int i = tid; i < (PPB * ROW) / 4; i += 256)
            __builtin_nontemporal_store(src[i], &dst[i]);
    }
    // out1: 64 contiguous floats = 16 float4
    if (tid < 16) {
        f32x4* dst = (f32x4*)(out + (size_t)npts * ROW + (size_t)blockIdx.x * (PPB * 8));
        __builtin_nontemporal_store(((const f32x4*)inst)[tid], &dst[tid]);
    }
}

extern "C" void kernel_launch(void* const* d_in, const int* in_sizes, int n_in,
                              void* d_out, int out_size, void* d_ws, size_t ws_size,
                              hipStream_t stream) {
    const float* xyz    = (const float*)d_in[0];
    const float* table  = (const float*)d_in[1];
    const int*   vmap   = (const int*)d_in[2];
    const float* voff   = (const float*)d_in[3];
    const float* vsize  = (const float*)d_in[4];
    const int*   vshape = (const int*)d_in[5];
    float* out = (float*)d_out;

    const int npts = in_sizes[0] / 3;      // 262144
    const int blocks = npts / PPB;         // 32768
    embed_voxel_kernel<<<blocks, 256, 0, stream>>>(xyz, table, vmap, voff, vsize,
                                                   vshape, out, npts);
}

// Round 6
// 99.676 us; speedup vs baseline: 2.0009x; 1.0007x over previous
//
#include <hip/hip_runtime.h>
#include <cstdint>

#define PPB 8      // points per block
#define ROW 351    // 32 + 32*4*2 + 3 + 3*10*2
#define CH 32

typedef float f32x4 __attribute__((ext_vector_type(4)));

#define INV2PI 0.15915494f   // matches ocml fast-sincos scale (0x3E22F983)

__global__ __launch_bounds__(256)
void embed_voxel_kernel(const float* __restrict__ xyz,
                        const float* __restrict__ table,
                        const int*   __restrict__ vmap,
                        const float* __restrict__ voff,
                        const float* __restrict__ vsize,
                        const int*   __restrict__ vshape,
                        float* __restrict__ out,
                        int npts)
{
    __shared__ __align__(16) float rows[PPB * ROW];   // 11232 B
    __shared__ __align__(16) float inst[PPB * 8];     // 256 B
    __shared__ float swt[PPB * 8];                    // corner weights
    __shared__ int   sidx[PPB * 8];                   // corner table indices

    const int tid = threadIdx.x;

    // ---- Phase A: one thread per (point,corner) — 64 threads.
    //      Each thread redundantly computes its point's coords (3 divides) —
    //      cheaper than an extra barrier-separated phase. ----
    if (tid < PPB * 8) {
        const int p = tid >> 3, k = tid & 7;
        const int sx = vshape[0], sy = vshape[1], sz = vshape[2];
        const float vs = vsize[0];
        const size_t n3 = ((size_t)blockIdx.x * PPB + p) * 3;
        float w = 1.0f;
        bool valid = true;
        int qq[3];
        #pragma unroll
        for (int d = 0; d < 3; ++d) {
            const float v = (xyz[n3 + d] + voff[d]) / vs;  // IEEE divide, matches ref
            const float fl = floorf(v);
            const float fr = v - fl;
            const int b = (k >> (2 - d)) & 1;
            const int qd = (int)fl + b;
            w *= b ? fr : 1.0f - fr;
            const int sd = (d == 0) ? sx : (d == 1) ? sy : sz;
            valid = valid && (qd >= 0) && (qd < sd);
            qq[d] = qd;
        }
        const int cqx = valid ? qq[0] : 0;
        const int cqy = valid ? qq[1] : 0;
        const int cqz = valid ? qq[2] : 0;
        const int id = vmap[((size_t)cqx * sy + cqy) * sz + cqz];
        swt[tid]  = (valid && id >= 0) ? w : 0.0f;
        sidx[tid] = (id >= 0) ? id : 0;
    }
    __syncthreads();

    // ---- Phase B: gather + weighted sum, one thread per (point,channel) ----
    const int p  = tid >> 5;
    const int ch = tid & 31;
    const size_t n3 = ((size_t)blockIdx.x * PPB + p) * 3;

    float acc = 0.0f;
    #pragma unroll
    for (int k = 0; k < 8; ++k) {
        const unsigned off = (unsigned)sidx[p * 8 + k] * CH + ch;  // 32-bit addressing
        acc = fmaf(swt[p * 8 + k], table[off], acc);
    }

    // ---- stage outputs into LDS (f32) ----
    float* r = rows + p * ROW;

    r[ch] = acc;                                   // voxel_ftr channels [0..31]
    if (ch >= 24) inst[p * 8 + (ch - 24)] = acc;   // inst = channels 24..31

    // posenc(voxel_ftr, 4): index = 32 + f*64 + s*32 + ch
    #pragma unroll
    for (int f = 0; f < 4; ++f) {
        const float t = acc * ((float)(1 << f) * INV2PI);   // exact pow2 scale
        r[32 + f * 64 + ch]      = __builtin_amdgcn_sinf(t);
        r[32 + f * 64 + 32 + ch] = __builtin_amdgcn_cosf(t);
    }

    // posenc(xyz, 10): raw xyz at 288+d, sin at 291+f*6+d, cos at 291+f*6+3+d
    if (ch < 3) r[288 + ch] = xyz[n3 + ch];
    if (ch < 30) {
        const int f = ch / 3, d = ch % 3;
        const float t = xyz[n3 + d] * ((float)(1 << f) * INV2PI);
        r[291 + f * 6 + d]     = __builtin_amdgcn_sinf(t);
        r[291 + f * 6 + 3 + d] = __builtin_amdgcn_cosf(t);
    }

    __syncthreads();

    // ---- coalesced non-temporal write-out ----
    // out0: this block's 8 rows = 2808 contiguous floats = 702 float4
    {
        f32x4* dst = (f32x4*)(out + (size_t)blockIdx.x * (PPB * ROW));
        const f32x4* src = (const f32x4*)rows;
        for (int i = tid; i < (PPB * ROW) / 4; i += 256)
            __builtin_nontemporal_store(src[i], &dst[i]);
    }
    // out1: 64 contiguous floats = 16 float4
    if (tid < 16) {
        f32x4* dst = (f32x4*)(out + (size_t)npts * ROW + (size_t)blockIdx.x * (PPB * 8));
        __builtin_nontemporal_store(((const f32x4*)inst)[tid], &dst[tid]);
    }
}

extern "C" void kernel_launch(void* const* d_in, const int* in_sizes, int n_in,
                              void* d_out, int out_size, void* d_ws, size_t ws_size,
                              hipStream_t stream) {
    const float* xyz    = (const float*)d_in[0];
    const float* table  = (const float*)d_in[1];
    const int*   vmap   = (const int*)d_in[2];
    const float* voff   = (const float*)d_in[3];
    const float* vsize  = (const float*)d_in[4];
    const int*   vshape = (const int*)d_in[5];
    float* out = (float*)d_out;

    const int npts = in_sizes[0] / 3;      // 262144
    const int blocks = npts / PPB;         // 32768
    embed_voxel_kernel<<<blocks, 256, 0, stream>>>(xyz, table, vmap, voff, vsize,
                                                   vshape, out, npts);
}